// Round 6
// baseline (640.326 us; speedup 1.0000x reference)
//
#include <hip/hip_runtime.h>
#include <hip/hip_cooperative_groups.h>

namespace cg = cooperative_groups;

// InfoNCE fwd+bwd on MI355X, single cooperative kernel (3 phases, 2 grid syncs).
// x (B=256, T=128, V=512) fp32, targets (B,T) int32, S=256.
// out[0] = total_loss, out[1:] = grad (B,T,V) fp32 (16,777,217 floats).

#define TT 128
#define VV 512
#define QSPLIT 8
#define TQ (TT / QSPLIT)  // 16 t-rows per phase-1 block
#define TC 8              // t-rows per LDS tile

typedef float f4 __attribute__((ext_vector_type(4)));

__device__ __forceinline__ float clip30(float v) {
  return fminf(fmaxf(v, -30.f), 30.f);
}

// async global->LDS, 16B per lane (wave-uniform LDS base + lane*16 layout)
__device__ __forceinline__ void gload16(const float* g, float* l) {
  __builtin_amdgcn_global_load_lds(
      (const __attribute__((address_space(1))) unsigned int*)g,
      (__attribute__((address_space(3))) unsigned int*)l, 16, 0, 0);
}

// ---------------------------------------------------------------------------
// Fused kernel: grid MUST be 2048 x 256 (8 blocks/CU co-resident).
// Phase 1: terms partials (block = (b, q)).
// Phase 2: softmax rows (blocks 0..255).
// Phase 3: grad tiles (2 tiles of 4096 floats per block).
// ---------------------------------------------------------------------------
__global__ __launch_bounds__(256) void fused_kernel(
    const float* __restrict__ x, const int* __restrict__ tgt,
    float* __restrict__ partial, float* __restrict__ coefT,
    float* __restrict__ losses, float* __restrict__ out) {
  cg::grid_group gg = cg::this_grid();
  int bid = blockIdx.x, s = threadIdx.x;
  int w = s >> 6, lane = s & 63;
  __shared__ __align__(16) float smem[TC * VV + 1];  // 16.4 KB, reused per phase
  __shared__ double dred[4];
  __shared__ float wred[8];

  // ---------------- phase 1: terms partial ----------------
  {
    int b = bid & 255, q = bid >> 8;
    const float* xb = x + ((size_t)b * TT + q * TQ) * VV;
    int4 tg[4];
#pragma unroll
    for (int k = 0; k < 4; ++k)
      tg[k] = ((const int4*)(tgt + (size_t)s * TT + q * TQ))[k];
    float acc = 0.f;
#pragma unroll
    for (int c = 0; c < 2; ++c) {
      const float* src = xb + c * TC * VV;  // 4096 floats
#pragma unroll
      for (int k = 0; k < 4; ++k)
        gload16(src + 4 * (s + k * 256), &smem[4 * (s + k * 256)]);
      __syncthreads();  // drains vmcnt for global_load_lds
      int4 a0 = tg[2 * c], a1 = tg[2 * c + 1];
      acc += clip30(smem[0 * VV + a0.x]) + clip30(smem[1 * VV + a0.y]) +
             clip30(smem[2 * VV + a0.z]) + clip30(smem[3 * VV + a0.w]) +
             clip30(smem[4 * VV + a1.x]) + clip30(smem[5 * VV + a1.y]) +
             clip30(smem[6 * VV + a1.z]) + clip30(smem[7 * VV + a1.w]);
      __syncthreads();
    }
    partial[(size_t)((q << 8) + b) * 256 + s] = acc;
  }

  gg.sync();

  // ---------------- phase 2: softmax (blocks 0..255) ----------------
  if (bid < 256) {
    int row = bid, b = s;
    float t = 0.f;
#pragma unroll
    for (int q = 0; q < QSPLIT; ++q)
      t += partial[(size_t)((q << 8) + b) * 256 + row];
    float m = t;
#pragma unroll
    for (int off = 32; off; off >>= 1) m = fmaxf(m, __shfl_xor(m, off));
    if (lane == 0) wred[w] = m;
    __syncthreads();
    m = fmaxf(fmaxf(wred[0], wred[1]), fmaxf(wred[2], wred[3]));
    float e = expf(t - m);
    float ssum = e;
#pragma unroll
    for (int off = 32; off; off >>= 1) ssum += __shfl_xor(ssum, off);
    if (lane == 0) wred[4 + w] = ssum;
    __syncthreads();
    float sum = wred[4] + wred[5] + wred[6] + wred[7];
    coefT[(b << 8) + row] = (b == row ? 1.f : 0.f) - e / sum;
    if (b == row) losses[row] = (t - m) - logf(sum);
  }

  gg.sync();

  // ---------------- phase 3: grad, two 4096-float tiles ----------------
  // Tile j covers out[j*4096 .. +4095] aligned; slot 0 = previous row's v=511
  // boundary element (or total loss for j==0); pad slot [4096] catches v=511
  // of row 7 (tile j+1's boundary; for j==4095 it's the final element).
#pragma unroll 1
  for (int tt = 0; tt < 2; ++tt) {
    int j = (bid << 1) | tt;
    int b = j >> 4, t0 = (j & 15) << 3;
    f4* rz = (f4*)smem;
    f4 zero = {0.f, 0.f, 0.f, 0.f};
#pragma unroll
    for (int k = 0; k < 4; ++k) rz[s + k * 256] = zero;
    if (s == 0) smem[TC * VV] = 0.f;

    float c = coefT[(b << 8) + s];
    int4 tg0 = *(const int4*)(tgt + (size_t)s * TT + t0);
    int4 tg1 = *(const int4*)(tgt + (size_t)s * TT + t0 + 4);

    float bc = 0.f;
    if (j > 0) {
      int R = j * 8 - 1;
      int bh = R >> 7, th = R & 127;
      if (tgt[(size_t)s * TT + th] == VV - 1) bc = coefT[(bh << 8) + s];
    }
    double ls = 0.0;
    if (j == 0) ls = (double)losses[s];

    __syncthreads();  // zeros visible
    atomicAdd(&smem[1 + 0 * VV + tg0.x], c);
    atomicAdd(&smem[1 + 1 * VV + tg0.y], c);
    atomicAdd(&smem[1 + 2 * VV + tg0.z], c);
    atomicAdd(&smem[1 + 3 * VV + tg0.w], c);
    atomicAdd(&smem[1 + 4 * VV + tg1.x], c);
    atomicAdd(&smem[1 + 5 * VV + tg1.y], c);
    atomicAdd(&smem[1 + 6 * VV + tg1.z], c);
    atomicAdd(&smem[1 + 7 * VV + tg1.w], c);
#pragma unroll
    for (int off = 32; off; off >>= 1) bc += __shfl_xor(bc, off);
    if (j > 0 && lane == 0) atomicAdd(&smem[0], bc);
    if (j == 0) {
#pragma unroll
      for (int off = 32; off; off >>= 1) ls += __shfl_xor(ls, off);
      if (lane == 0) dred[w] = ls;
    }
    __syncthreads();  // scatter + dred done
    if (j == 0 && s == 0) smem[0] = (float)(dred[0] + dred[1] + dred[2] + dred[3]);
    __syncthreads();  // smem[0] visible

    f4* go = (f4*)(out + (size_t)j * 4096);
#pragma unroll
    for (int k = 0; k < 4; ++k)
      __builtin_nontemporal_store(rz[s + k * 256], &go[s + k * 256]);
    if (j == 4095 && s == 0) out[(size_t)4096 * 4096] = smem[TC * VV];
  }
}

// ===========================================================================
// Fallback path: the proven 3-kernel pipeline (used if cooperative launch
// is rejected by the runtime / graph capture).
// ===========================================================================
__global__ __launch_bounds__(256) void terms_kernel(
    const float* __restrict__ x, const int* __restrict__ tgt,
    float* __restrict__ partial) {
  int bid = blockIdx.x;
  int b = bid & 255, q = bid >> 8, s = threadIdx.x;
  __shared__ __align__(16) float xch[TC * VV];
  const float* xb = x + ((size_t)b * TT + q * TQ) * VV;
  int4 tg[4];
#pragma unroll
  for (int k = 0; k < 4; ++k)
    tg[k] = ((const int4*)(tgt + (size_t)s * TT + q * TQ))[k];
  float acc = 0.f;
#pragma unroll
  for (int c = 0; c < 2; ++c) {
    const float* src = xb + c * TC * VV;
#pragma unroll
    for (int k = 0; k < 4; ++k)
      gload16(src + 4 * (s + k * 256), &xch[4 * (s + k * 256)]);
    __syncthreads();
    int4 a0 = tg[2 * c], a1 = tg[2 * c + 1];
    acc += clip30(xch[0 * VV + a0.x]) + clip30(xch[1 * VV + a0.y]) +
           clip30(xch[2 * VV + a0.z]) + clip30(xch[3 * VV + a0.w]) +
           clip30(xch[4 * VV + a1.x]) + clip30(xch[5 * VV + a1.y]) +
           clip30(xch[6 * VV + a1.z]) + clip30(xch[7 * VV + a1.w]);
    __syncthreads();
  }
  partial[(size_t)((q << 8) + b) * 256 + s] = acc;
}

__global__ __launch_bounds__(256) void softmax_kernel(
    const float* __restrict__ partial, float* __restrict__ coefT,
    float* __restrict__ losses) {
  int row = blockIdx.x, b = threadIdx.x;
  int w = b >> 6, lane = b & 63;
  float t = 0.f;
#pragma unroll
  for (int q = 0; q < QSPLIT; ++q)
    t += partial[(size_t)((q << 8) + b) * 256 + row];
  float m = t;
#pragma unroll
  for (int off = 32; off; off >>= 1) m = fmaxf(m, __shfl_xor(m, off));
  __shared__ float wm[4], ws[4];
  if (lane == 0) wm[w] = m;
  __syncthreads();
  m = fmaxf(fmaxf(wm[0], wm[1]), fmaxf(wm[2], wm[3]));
  float e = expf(t - m);
  float ssum = e;
#pragma unroll
  for (int off = 32; off; off >>= 1) ssum += __shfl_xor(ssum, off);
  if (lane == 0) ws[w] = ssum;
  __syncthreads();
  float sum = ws[0] + ws[1] + ws[2] + ws[3];
  coefT[(b << 8) + row] = (b == row ? 1.f : 0.f) - e / sum;
  if (b == row) losses[row] = (t - m) - logf(sum);
}

__global__ __launch_bounds__(256) void grad_kernel(
    const float* __restrict__ coefT, const int* __restrict__ tgt,
    const float* __restrict__ losses, float* __restrict__ out) {
  int j = blockIdx.x, s = threadIdx.x;
  int w = s >> 6, lane = s & 63;
  int b = j >> 4, t0 = (j & 15) << 3;
  __shared__ __align__(16) float rows[TC * VV + 1];
  __shared__ double dred[4];
  f4* rz = (f4*)rows;
  f4 zero = {0.f, 0.f, 0.f, 0.f};
#pragma unroll
  for (int k = 0; k < 4; ++k) rz[s + k * 256] = zero;
  if (s == 0) rows[TC * VV] = 0.f;

  float c = coefT[(b << 8) + s];
  int4 tg0 = *(const int4*)(tgt + (size_t)s * TT + t0);
  int4 tg1 = *(const int4*)(tgt + (size_t)s * TT + t0 + 4);

  float bc = 0.f;
  if (j > 0) {
    int R = j * 8 - 1;
    int bh = R >> 7, th = R & 127;
    if (tgt[(size_t)s * TT + th] == VV - 1) bc = coefT[(bh << 8) + s];
  }
  double ls = 0.0;
  if (j == 0) ls = (double)losses[s];

  __syncthreads();
  atomicAdd(&rows[1 + 0 * VV + tg0.x], c);
  atomicAdd(&rows[1 + 1 * VV + tg0.y], c);
  atomicAdd(&rows[1 + 2 * VV + tg0.z], c);
  atomicAdd(&rows[1 + 3 * VV + tg0.w], c);
  atomicAdd(&rows[1 + 4 * VV + tg1.x], c);
  atomicAdd(&rows[1 + 5 * VV + tg1.y], c);
  atomicAdd(&rows[1 + 6 * VV + tg1.z], c);
  atomicAdd(&rows[1 + 7 * VV + tg1.w], c);
#pragma unroll
  for (int off = 32; off; off >>= 1) bc += __shfl_xor(bc, off);
  if (j > 0 && lane == 0) atomicAdd(&rows[0], bc);
  if (j == 0) {
#pragma unroll
    for (int off = 32; off; off >>= 1) ls += __shfl_xor(ls, off);
    if (lane == 0) dred[w] = ls;
  }
  __syncthreads();
  if (j == 0 && s == 0) rows[0] = (float)(dred[0] + dred[1] + dred[2] + dred[3]);
  __syncthreads();

  f4* go = (f4*)(out + (size_t)j * 4096);
#pragma unroll
  for (int k = 0; k < 4; ++k)
    __builtin_nontemporal_store(rz[s + k * 256], &go[s + k * 256]);
  if (j == 4095 && s == 0) out[(size_t)4096 * 4096] = rows[TC * VV];
}

extern "C" void kernel_launch(void* const* d_in, const int* in_sizes, int n_in,
                              void* d_out, int out_size, void* d_ws, size_t ws_size,
                              hipStream_t stream) {
  const float* x = (const float*)d_in[0];
  const int* tgt = (const int*)d_in[1];
  float* out = (float*)d_out;

  float* partial = (float*)d_ws;                  // 8*256*256 floats (2 MiB)
  float* coefT = partial + QSPLIT * 256 * 256;    // 256*256 floats
  float* losses = coefT + 256 * 256;              // 256 floats

  void* args[] = {(void*)&x, (void*)&tgt, (void*)&partial,
                  (void*)&coefT, (void*)&losses, (void*)&out};
  hipError_t err = hipLaunchCooperativeKernel(
      (const void*)fused_kernel, dim3(2048), dim3(256), args, 0, stream);
  if (err != hipSuccess) {
    // fallback: proven 3-kernel pipeline
    terms_kernel<<<dim3(2048), dim3(256), 0, stream>>>(x, tgt, partial);
    softmax_kernel<<<dim3(256), dim3(256), 0, stream>>>(partial, coefT, losses);
    grad_kernel<<<dim3(4096), dim3(256), 0, stream>>>(coefT, tgt, losses, out);
  }
}

// Round 8
// 166.564 us; speedup vs baseline: 3.8443x; 3.8443x over previous
//
#include <hip/hip_runtime.h>

// InfoNCE fwd+bwd on MI355X. 3-kernel pipeline.
// x (B=256, T=128, V=512) fp32, targets (B,T) int32, S=256.
// out[0] = total_loss, out[1:] = grad (B,T,V) fp32 (16,777,217 floats).

#define TT 128
#define VV 512
#define QSPLIT 8
#define TQ (TT / QSPLIT)  // 16 t-rows per terms/grad block

typedef float f4 __attribute__((ext_vector_type(4)));

__device__ __forceinline__ float clip30(float v) {
  return fminf(fmaxf(v, -30.f), 30.f);
}

// ---------------------------------------------------------------------------
// Kernel A: terms partials, DIRECT GATHER (no LDS, no barriers).
// grid = 2048 (b = bid&255, q = bid>>8), 256 threads (thread = s).
// partial[q][b][s] = sum_{r=0..15} clip(x[b, q*16+r, tgt[s, q*16+r]]).
// All 64 lanes of a wave read the same 2KB x-row -> ~28 lines/instr, row
// fetched once from HBM, re-reads served by L1/L2. 16 independent loads per
// thread give deep ILP; 8 blocks/CU give TLP. No vmcnt(0) drains anywhere.
// ---------------------------------------------------------------------------
__global__ __launch_bounds__(256) void terms_kernel(
    const float* __restrict__ x, const int* __restrict__ tgt,
    float* __restrict__ partial) {
  int bid = blockIdx.x;
  int b = bid & 255, q = bid >> 8, s = threadIdx.x;
  int4 tg[4];
#pragma unroll
  for (int k = 0; k < 4; ++k)
    tg[k] = ((const int4*)(tgt + (size_t)s * TT + q * TQ))[k];
  const float* xb = x + ((size_t)b * TT + q * TQ) * VV;
  float a0 = 0.f, a1 = 0.f, a2 = 0.f, a3 = 0.f;
#pragma unroll
  for (int k = 0; k < 4; ++k) {
    a0 += clip30(xb[(4 * k + 0) * VV + tg[k].x]);
    a1 += clip30(xb[(4 * k + 1) * VV + tg[k].y]);
    a2 += clip30(xb[(4 * k + 2) * VV + tg[k].z]);
    a3 += clip30(xb[(4 * k + 3) * VV + tg[k].w]);
  }
  partial[(size_t)((q << 8) + b) * 256 + s] = (a0 + a1) + (a2 + a3);
}

// ---------------------------------------------------------------------------
// Kernel B: per-row softmax/logsumexp. grid = 256 (row s), 256 threads (b).
// coefT[b][s] = (b==s) - softmax(terms[s,:])[b];  losses[s] = terms[s,s]-lse.
// ---------------------------------------------------------------------------
__global__ __launch_bounds__(256) void softmax_kernel(
    const float* __restrict__ partial, float* __restrict__ coefT,
    float* __restrict__ losses) {
  int row = blockIdx.x, b = threadIdx.x;
  int w = b >> 6, lane = b & 63;
  float t = 0.f;
#pragma unroll
  for (int q = 0; q < QSPLIT; ++q)
    t += partial[(size_t)((q << 8) + b) * 256 + row];
  float m = t;
#pragma unroll
  for (int off = 32; off; off >>= 1) m = fmaxf(m, __shfl_xor(m, off));
  __shared__ float wm[4], ws[4];
  if (lane == 0) wm[w] = m;
  __syncthreads();
  m = fmaxf(fmaxf(wm[0], wm[1]), fmaxf(wm[2], wm[3]));
  float e = expf(t - m);
  float ssum = e;
#pragma unroll
  for (int off = 32; off; off >>= 1) ssum += __shfl_xor(ssum, off);
  if (lane == 0) ws[w] = ssum;
  __syncthreads();
  float sum = ws[0] + ws[1] + ws[2] + ws[3];
  coefT[(b << 8) + row] = (b == row ? 1.f : 0.f) - e / sum;
  if (b == row) losses[row] = (t - m) - logf(sum);
}

// ---------------------------------------------------------------------------
// Kernel C: grad scatter + aligned stream-out. grid = 2048, 256 threads.
// Block k covers out[k*8192 .. k*8192+8191] (two 4096-float tiles, same b):
//   local u=0        = grad flat (k*8192-1)  [row k*16-1, v=511] or loss (k==0)
//   local u=1..8191  = grad flat (k*8192-1+u)
//   pad   u=8192     = grad flat (k*8192+8191) -> next block's u=0
//                      (for k==2047 it is the final element out[2^24]).
// 16 t-rows scattered per block; 2 barriers total; 8 f4 NT stores per thread.
// ---------------------------------------------------------------------------
__global__ __launch_bounds__(256) void grad_kernel(
    const float* __restrict__ coefT, const int* __restrict__ tgt,
    const float* __restrict__ losses, float* __restrict__ out) {
  int k = blockIdx.x, s = threadIdx.x;
  int w = s >> 6, lane = s & 63;
  int b = k >> 3, t0 = (k & 7) << 4;
  __shared__ __align__(16) float smem[16 * VV + 1];  // 8193 floats, 32.8 KB
  __shared__ double dred[4];

  // hoisted loads (issue before the zero-phase barrier; HBM latency overlaps)
  float c = coefT[(b << 8) + s];
  int4 tg[4];
#pragma unroll
  for (int m = 0; m < 4; ++m)
    tg[m] = ((const int4*)(tgt + (size_t)s * TT + t0))[m];
  float bc = 0.f;
  double ls = 0.0;
  if (k > 0) {
    int R = (k << 4) - 1;             // global row before this block
    int bh = R >> 7, th = R & 127;
    if (tgt[(size_t)s * TT + th] == VV - 1) bc = coefT[(bh << 8) + s];
  } else {
    ls = (double)losses[s];
  }

  // zero phase
  f4* rz = (f4*)smem;
  f4 zero = {0.f, 0.f, 0.f, 0.f};
#pragma unroll
  for (int m = 0; m < 8; ++m) rz[s + m * 256] = zero;
  if (s == 0) smem[16 * VV] = 0.f;
  __syncthreads();  // barrier 1: zeros visible

  // scatter phase: row r (t = t0+r) target v -> u = 1 + r*512 + v
#pragma unroll
  for (int m = 0; m < 4; ++m) {
    atomicAdd(&smem[1 + (4 * m + 0) * VV + tg[m].x], c);
    atomicAdd(&smem[1 + (4 * m + 1) * VV + tg[m].y], c);
    atomicAdd(&smem[1 + (4 * m + 2) * VV + tg[m].z], c);
    atomicAdd(&smem[1 + (4 * m + 3) * VV + tg[m].w], c);
  }
#pragma unroll
  for (int off = 32; off; off >>= 1) bc += __shfl_xor(bc, off);
  if (k > 0 && lane == 0) atomicAdd(&smem[0], bc);
  if (k == 0) {
#pragma unroll
    for (int off = 32; off; off >>= 1) ls += __shfl_xor(ls, off);
    if (lane == 0) dred[w] = ls;
  }
  __syncthreads();  // barrier 2: scatter + dred done

  // k==0: only thread 0 touches smem[0] after this point (it stores chunk 0)
  if (k == 0 && s == 0)
    smem[0] = (float)(dred[0] + dred[1] + dred[2] + dred[3]);

  // store phase: 8192 floats, aligned f4 both sides
  f4* go = (f4*)(out + (size_t)k * 8192);
#pragma unroll
  for (int m = 0; m < 8; ++m)
    __builtin_nontemporal_store(rz[s + m * 256], &go[s + m * 256]);
  if (k == 2047 && s == 0) out[(size_t)4096 * 4096] = smem[16 * VV];
}

extern "C" void kernel_launch(void* const* d_in, const int* in_sizes, int n_in,
                              void* d_out, int out_size, void* d_ws, size_t ws_size,
                              hipStream_t stream) {
  const float* x = (const float*)d_in[0];
  const int* tgt = (const int*)d_in[1];
  float* out = (float*)d_out;

  float* partial = (float*)d_ws;                  // 8*256*256 floats (2 MiB)
  float* coefT = partial + QSPLIT * 256 * 256;    // 256*256 floats
  float* losses = coefT + 256 * 256;              // 256 floats

  terms_kernel<<<dim3(2048), dim3(256), 0, stream>>>(x, tgt, partial);
  softmax_kernel<<<dim3(256), dim3(256), 0, stream>>>(partial, coefT, losses);
  grad_kernel<<<dim3(2048), dim3(256), 0, stream>>>(coefT, tgt, losses, out);
}